// Round 5
// baseline (311.581 us; speedup 1.0000x reference)
//
#include <hip/hip_runtime.h>
#include <hip/hip_bf16.h>
#include <math.h>

#define NB   1024    // key blocks per batch
#define HKH  8       // Hk

typedef float f4 __attribute__((ext_vector_type(4)));

// ---------------- Fused kernel: qgate + pool + project + rmsnorm/rope + dot --
// grid = B(4) * H(8) * TILES(32) = 1024 wg, 256 threads.
// Per wg: (1) redundantly compute this (b,h)'s query gate vector (cheap, one
// residency round), (2) stream 32 key-blocks' head-slice, pool mean/max in
// regs, write transposed A to LDS At[256][36], (3) 32x128 K=256 GEMM with A
// from LDS (b128) and W direct from L2 (coalesced 512B), fused epilogue.
__global__ __launch_bounds__(256) void fused_kernel(const float* __restrict__ kin,
                                                    const float* __restrict__ qrow,
                                                    const float* __restrict__ Wq,
                                                    const float* __restrict__ Wk,
                                                    const float* __restrict__ qnw,
                                                    const float* __restrict__ knw,
                                                    const float* __restrict__ cq,
                                                    const float* __restrict__ sq,
                                                    const float* __restrict__ cosk,
                                                    const float* __restrict__ sink,
                                                    float* __restrict__ scores) {
    __shared__ float At[256][36];   // k-major pooled tile, pad->f4-aligned rows
    __shared__ float qs[512];
    int wg   = blockIdx.x;
    int tile = wg & 31;
    int h    = (wg >> 5) & 7;
    int b    = wg >> 8;
    int t    = threadIdx.x;
    int tc   = t & 31;              // col-group: cols 4tc..4tc+3
    int tr   = t >> 5;              // row-group: rows 4tr..4tr+3 (and pool half-wave)

    // ---- Phase 0: query gate (redundant per wg; o = 4tc+j) ----
    qs[t]       = qrow[(size_t)b * 4096 + (size_t)h * 512 + t];
    qs[t + 256] = qrow[(size_t)b * 4096 + (size_t)h * 512 + t + 256];
    __syncthreads();
    float qv[4];
    {
        const float* wq = Wq + (size_t)h * 512 * 128 + tc * 4;
        float aq[4] = {0.f, 0.f, 0.f, 0.f};
#pragma unroll 4
        for (int gi = 0; gi < 512; ++gi) {
            f4 w = *(const f4*)(wq + (size_t)gi * 128);
            float qg = qs[gi];
            aq[0] = fmaf(qg, w.x, aq[0]); aq[1] = fmaf(qg, w.y, aq[1]);
            aq[2] = fmaf(qg, w.z, aq[2]); aq[3] = fmaf(qg, w.w, aq[3]);
        }
        float ss = aq[0]*aq[0] + aq[1]*aq[1] + aq[2]*aq[2] + aq[3]*aq[3];
#pragma unroll
        for (int off = 1; off < 32; off <<= 1) ss += __shfl_xor(ss, off);
        float scale = rsqrtf(ss * (1.0f / 128.0f) + 1e-6f);
#pragma unroll
        for (int j = 0; j < 4; ++j) {
            int o = tc * 4 + j;
            float y  = aq[j] * scale * qnw[o];
            float yp = __shfl_xor(y, 16);             // partner col o +/- 64
            float rot = (tc < 16) ? -yp : yp;
            qv[j] = fmaf(y, cq[b * 128 + o], rot * sq[b * 128 + o]);
        }
    }
    __syncthreads();   // qs dead; safe before At writes (distinct arrays anyway)

    // ---- Phase 1: pool 32 blocks; half-wave tr owns blocks 4tr..4tr+3 ----
    {
        const float inv = 1.0f / 64.0f;
#pragma unroll
        for (int bi = 0; bi < 4; ++bi) {
            int blk = tr * 4 + bi;                    // local block 0..31
            size_t row0 = (size_t)b * 65536 + ((size_t)tile * 32 + blk) * 64;
            const f4* src = (const f4*)(kin + row0 * 1024 + (size_t)h * 128) + tc;
            f4 v = __builtin_nontemporal_load(src);
            f4 s = v, m = v;
#pragma unroll 8
            for (int r = 1; r < 64; ++r) {
                f4 u = __builtin_nontemporal_load(src + (size_t)r * 256);
                s += u;
                m.x = fmaxf(m.x, u.x); m.y = fmaxf(m.y, u.y);
                m.z = fmaxf(m.z, u.z); m.w = fmaxf(m.w, u.w);
            }
            int k0 = tc * 4;
            At[k0 + 0][blk] = s.x * inv; At[k0 + 1][blk] = s.y * inv;
            At[k0 + 2][blk] = s.z * inv; At[k0 + 3][blk] = s.w * inv;
            At[128 + k0 + 0][blk] = m.x; At[128 + k0 + 1][blk] = m.y;
            At[128 + k0 + 2][blk] = m.z; At[128 + k0 + 3][blk] = m.w;
        }
    }
    __syncthreads();

    // ---- Phase 2: GEMM 32x128, K=256; A from LDS, W from L2 ----
    float acc[4][4];
#pragma unroll
    for (int i = 0; i < 4; ++i)
#pragma unroll
        for (int j = 0; j < 4; ++j) acc[i][j] = 0.0f;
    const float* Wb = Wk + (size_t)h * 256 * 128 + tc * 4;
#pragma unroll 8
    for (int k = 0; k < 256; ++k) {
        f4 a = *(const f4*)&At[k][tr * 4];
        f4 w = *(const f4*)(Wb + (size_t)k * 128);
        acc[0][0] = fmaf(a.x, w.x, acc[0][0]); acc[0][1] = fmaf(a.x, w.y, acc[0][1]);
        acc[0][2] = fmaf(a.x, w.z, acc[0][2]); acc[0][3] = fmaf(a.x, w.w, acc[0][3]);
        acc[1][0] = fmaf(a.y, w.x, acc[1][0]); acc[1][1] = fmaf(a.y, w.y, acc[1][1]);
        acc[1][2] = fmaf(a.y, w.z, acc[1][2]); acc[1][3] = fmaf(a.y, w.w, acc[1][3]);
        acc[2][0] = fmaf(a.z, w.x, acc[2][0]); acc[2][1] = fmaf(a.z, w.y, acc[2][1]);
        acc[2][2] = fmaf(a.z, w.z, acc[2][2]); acc[2][3] = fmaf(a.z, w.w, acc[2][3]);
        acc[3][0] = fmaf(a.w, w.x, acc[3][0]); acc[3][1] = fmaf(a.w, w.y, acc[3][1]);
        acc[3][2] = fmaf(a.w, w.z, acc[3][2]); acc[3][3] = fmaf(a.w, w.w, acc[3][3]);
    }

    // ---- Epilogue: per-row rmsnorm + rope + dot(qv) ----
    float kn[4];
#pragma unroll
    for (int j = 0; j < 4; ++j) kn[j] = knw[tc * 4 + j];
#pragma unroll
    for (int i = 0; i < 4; ++i) {
        int blkg = tile * 32 + tr * 4 + i;
        float ss = 0.0f;
#pragma unroll
        for (int j = 0; j < 4; ++j) ss = fmaf(acc[i][j], acc[i][j], ss);
#pragma unroll
        for (int off = 1; off < 32; off <<= 1) ss += __shfl_xor(ss, off);
        float scale = rsqrtf(ss * (1.0f / 128.0f) + 1e-6f);
        const float* cb = cosk + ((size_t)b * NB + blkg) * 128;
        const float* sb = sink + ((size_t)b * NB + blkg) * 128;
        float part = 0.0f;
#pragma unroll
        for (int j = 0; j < 4; ++j) {
            int o = tc * 4 + j;
            float y  = acc[i][j] * scale * kn[j];
            float yp = __shfl_xor(y, 16);
            float rot = (tc < 16) ? -yp : yp;
            float z = fmaf(y, cb[o], rot * sb[o]);
            part = fmaf(z, qv[j], part);
        }
#pragma unroll
        for (int off = 1; off < 32; off <<= 1) part += __shfl_xor(part, off);
        if (tc == 0)
            scores[((size_t)b * HKH + h) * NB + blkg] = part * 0.08838834764831845f;
    }
}

// ---------------- Kernel D: rank-by-counting top-k -> int32 mask ----------
__device__ inline bool read_mask(const void* amp, int mode, size_t idx) {
    if (mode == 1) return ((const int*)amp)[idx] != 0;
    if (mode == 2) return ((const unsigned int*)amp)[idx] != 0u;
    return ((const unsigned char*)amp)[idx] != 0;
}

__global__ __launch_bounds__(512) void topk_kernel(const float* __restrict__ scores,
                                                   const void* __restrict__ amraw,
                                                   const int* __restrict__ bbp,
                                                   int* __restrict__ out) {
    int b = blockIdx.x >> 3, h = blockIdx.x & 7;
    int t = threadIdx.x;
    __shared__ float sv[NB];
    __shared__ int mode_sh;

    if (t == 0) {
        // classify attention_mask dtype from raw bit patterns
        const unsigned int* w = (const unsigned int*)amraw;
        bool allint = true, allflt = true;
        for (int i = 0; i < 64; ++i) {
            unsigned int x = w[i];
            if (x != 0u && x != 1u) allint = false;
            if (x != 0u && x != 0x3f800000u) allflt = false;
        }
        mode_sh = allint ? 1 : (allflt ? 2 : 0);
    }
    __syncthreads();
    int mode = mode_sh;
    size_t rowoff = ((size_t)b * HKH + h) * NB;
    const float* src = scores + rowoff;
    for (int s = t; s < NB; s += 512)
        sv[s] = read_mask(amraw, mode, rowoff + s) ? src[s] : -1e20f;
    __syncthreads();

    int bb = bbp[0];
    if (bb > NB) bb = NB;
    if (bb < 1)  bb = 1;

    int e0 = t, e1 = t + 512;
    float v0 = sv[e0], v1 = sv[e1];
    int r0 = 0, r1 = 0;   // rank = #gt + #eq-at-lower-index
#pragma unroll 4
    for (int j4 = 0; j4 < 256; ++j4) {
        f4 w = *(const f4*)&sv[j4 * 4];
        int jb = j4 * 4;
        r0 += (w.x > v0) + (w.y > v0) + (w.z > v0) + (w.w > v0);
        r1 += (w.x > v1) + (w.y > v1) + (w.z > v1) + (w.w > v1);
        r0 += (w.x == v0 && jb + 0 < e0) + (w.y == v0 && jb + 1 < e0)
            + (w.z == v0 && jb + 2 < e0) + (w.w == v0 && jb + 3 < e0);
        r1 += (w.x == v1 && jb + 0 < e1) + (w.y == v1 && jb + 1 < e1)
            + (w.z == v1 && jb + 2 < e1) + (w.w == v1 && jb + 3 < e1);
    }
    int* dst = out + rowoff;
    bool am0 = read_mask(amraw, mode, rowoff + e0);
    bool am1 = read_mask(amraw, mode, rowoff + e1);
    dst[e0] = ((r0 < bb && am0)) ? 1 : 0;
    dst[e1] = ((r1 < bb && am1) || (e1 == NB - 1)) ? 1 : 0;
}

extern "C" void kernel_launch(void* const* d_in, const int* in_sizes, int n_in,
                              void* d_out, int out_size, void* d_ws, size_t ws_size,
                              hipStream_t stream) {
    (void)in_sizes; (void)n_in; (void)out_size; (void)ws_size;
    const float* k   = (const float*)d_in[0];
    const float* q   = (const float*)d_in[1];
    const float* Wq  = (const float*)d_in[2];
    const float* Wk  = (const float*)d_in[3];
    const float* qnw = (const float*)d_in[4];
    const float* knw = (const float*)d_in[5];
    const float* cq  = (const float*)d_in[6];
    const float* sq  = (const float*)d_in[7];
    const float* ck  = (const float*)d_in[8];
    const float* sk  = (const float*)d_in[9];
    const void*  am  = d_in[10];
    const int*   bb  = (const int*)d_in[11];
    int* out = (int*)d_out;

    float* scores = (float*)d_ws;                 // 4*8*1024 floats

    fused_kernel<<<1024, 256, 0, stream>>>(k, q, Wq, Wk, qnw, knw,
                                           cq, sq, ck, sk, scores);
    topk_kernel<<<32, 512, 0, stream>>>(scores, am, bb, out);
}

// Round 6
// 285.653 us; speedup vs baseline: 1.0908x; 1.0908x over previous
//
#include <hip/hip_runtime.h>
#include <hip/hip_bf16.h>
#include <math.h>

#define NB   1024    // key blocks per batch
#define HKH  8       // Hk

typedef float f4 __attribute__((ext_vector_type(4)));

// ---------------- Kernel Q: query gate projection -----------------
// grid = B*HK = 32 blocks, 512 threads (4-way K split per output dim).
__global__ __launch_bounds__(512) void qproj_kernel(const float* __restrict__ q,
                                                    const float* __restrict__ Wq,
                                                    const float* __restrict__ qnw,
                                                    const float* __restrict__ cq,
                                                    const float* __restrict__ sq,
                                                    float* __restrict__ qv) {
    int b = blockIdx.x >> 3, h = blockIdx.x & 7;
    int t = threadIdx.x;
    int o = t & 127, seg = t >> 7;
    __shared__ float qs[512];
    __shared__ float part[4][128];
    __shared__ float red[2];
    __shared__ float ybuf[128];
    qs[t] = q[(size_t)b * 4096 + (size_t)h * 512 + t];
    __syncthreads();
    const float* wqp = Wq + (size_t)h * 512 * 128 + o;
    float acc = 0.0f;
    int g0 = seg * 128;
#pragma unroll 4
    for (int gi = g0; gi < g0 + 128; ++gi)
        acc = fmaf(qs[gi], wqp[(size_t)gi * 128], acc);
    part[seg][o] = acc;
    __syncthreads();
    if (t < 128) {
        float a = part[0][o] + part[1][o] + part[2][o] + part[3][o];
        ybuf[o] = a;
        float ss = a * a;
        for (int off = 32; off > 0; off >>= 1) ss += __shfl_xor(ss, off);
        if ((o & 63) == 0) red[o >> 6] = ss;
    }
    __syncthreads();
    if (t < 128) {
        float scale = rsqrtf((red[0] + red[1]) * (1.0f / 128.0f) + 1e-6f);
        float y  = ybuf[o] * scale * qnw[o];
        int op   = (o < 64) ? o + 64 : o - 64;
        float yp = ybuf[op] * scale * qnw[op];
        float rot = (o < 64) ? -yp : yp;
        qv[((size_t)b * HKH + h) * 128 + o] =
            fmaf(y, cq[b * 128 + o], rot * sq[b * 128 + o]);
    }
}

// ---------------- Fused kernel: pool + project + rmsnorm/rope + dot ---------
// grid = B(4) * TILES(32) * H(8) = 1024 wg (h fastest: 8 consecutive wgs read
// complementary 512B slices of the same 4KB DRAM rows). 256 threads.
// Phase 1: stream 32 blocks' head-slice, pool mean/max in regs, write A-tile
// row-major [32][256] with per-row XOR f4-swizzle (b128 writes AND reads).
// Phase 2: GEMM 32x128 K=256; A from LDS b128 (4k per read), W from L2
// (256B/wave, L2-resident since k loads are nontemporal); 2x8 register tile
// -> VALU-bound inner loop. Fused rmsnorm/rope/dot epilogue.
__global__ __launch_bounds__(256) void fused_kernel(const float* __restrict__ kin,
                                                    const float* __restrict__ Wk,
                                                    const float* __restrict__ knw,
                                                    const float* __restrict__ cosk,
                                                    const float* __restrict__ sink,
                                                    const float* __restrict__ qv,
                                                    float* __restrict__ scores) {
    __shared__ float At[32][256];   // row-major, f4-swizzled: f4c' = f4c ^ (row&7)
    int wg   = blockIdx.x;
    int h    = wg & 7;
    int tile = (wg >> 3) & 31;
    int b    = wg >> 8;
    int t    = threadIdx.x;

    // ---- Phase 1: pool; group tr (t>>5, 0..7) owns blocks 4tr..4tr+3 ----
    {
        int tc = t & 31;            // f4 column within 128-float head slice
        int tr = t >> 5;
        const float inv = 1.0f / 64.0f;
#pragma unroll
        for (int bi = 0; bi < 4; ++bi) {
            int blk = tr * 4 + bi;                    // local block 0..31
            size_t row0 = (size_t)b * 65536 + ((size_t)tile * 32 + blk) * 64;
            const f4* src = (const f4*)(kin + row0 * 1024 + (size_t)h * 128) + tc;
            f4 v = __builtin_nontemporal_load(src);
            f4 s = v, m = v;
#pragma unroll 8
            for (int r = 1; r < 64; ++r) {
                f4 u = __builtin_nontemporal_load(src + (size_t)r * 256);
                s += u;
                m.x = fmaxf(m.x, u.x); m.y = fmaxf(m.y, u.y);
                m.z = fmaxf(m.z, u.z); m.w = fmaxf(m.w, u.w);
            }
            int sw = blk & 7;
            f4 mean = { s.x * inv, s.y * inv, s.z * inv, s.w * inv };
            *(f4*)&At[blk][(tc ^ sw) << 2]        = mean;   // f4c 0..31 = mean
            *(f4*)&At[blk][((tc + 32) ^ sw) << 2] = m;      // f4c 32..63 = max
        }
    }
    __syncthreads();

    // ---- Phase 2: GEMM 32x128, K=256; 2 rows x 8 cols per thread ----
    int cg = t & 15;                // cols 8cg..8cg+7
    int rg = t >> 4;                // rows 2rg, 2rg+1
    int r0 = rg * 2, r1 = r0 + 1;
    int s0 = r0 & 7, s1 = r1 & 7;
    float acc0[8], acc1[8];
#pragma unroll
    for (int j = 0; j < 8; ++j) { acc0[j] = 0.0f; acc1[j] = 0.0f; }
    const float* Wb = Wk + (size_t)h * 256 * 128 + cg * 8;
#pragma unroll 2
    for (int kq = 0; kq < 64; ++kq) {       // 4 k-steps per iteration
        f4 a0 = *(const f4*)&At[r0][(kq ^ s0) << 2];
        f4 a1 = *(const f4*)&At[r1][(kq ^ s1) << 2];
        const float* wrow = Wb + (size_t)kq * 512;
#pragma unroll
        for (int dk = 0; dk < 4; ++dk) {
            f4 w0 = *(const f4*)(wrow + dk * 128);
            f4 w1 = *(const f4*)(wrow + dk * 128 + 4);
            float av0 = a0[dk], av1 = a1[dk];
            acc0[0] = fmaf(av0, w0.x, acc0[0]); acc0[1] = fmaf(av0, w0.y, acc0[1]);
            acc0[2] = fmaf(av0, w0.z, acc0[2]); acc0[3] = fmaf(av0, w0.w, acc0[3]);
            acc0[4] = fmaf(av0, w1.x, acc0[4]); acc0[5] = fmaf(av0, w1.y, acc0[5]);
            acc0[6] = fmaf(av0, w1.z, acc0[6]); acc0[7] = fmaf(av0, w1.w, acc0[7]);
            acc1[0] = fmaf(av1, w0.x, acc1[0]); acc1[1] = fmaf(av1, w0.y, acc1[1]);
            acc1[2] = fmaf(av1, w0.z, acc1[2]); acc1[3] = fmaf(av1, w0.w, acc1[3]);
            acc1[4] = fmaf(av1, w1.x, acc1[4]); acc1[5] = fmaf(av1, w1.y, acc1[5]);
            acc1[6] = fmaf(av1, w1.z, acc1[6]); acc1[7] = fmaf(av1, w1.w, acc1[7]);
        }
    }

    // ---- Epilogue: per-row rmsnorm + rope + dot(qv) ----
    // thread cols: o = 8cg+j (j 0..7); partner o+/-64 lives at lane cg^8.
    float kn[8], qvr[8];
    const float* qvp = qv + ((size_t)b * HKH + h) * 128 + cg * 8;
#pragma unroll
    for (int j = 0; j < 8; ++j) { kn[j] = knw[cg * 8 + j]; qvr[j] = qvp[j]; }
#pragma unroll
    for (int i = 0; i < 2; ++i) {
        float* acc = i ? acc1 : acc0;
        int blkg = tile * 32 + r0 + i;
        float ss = 0.0f;
#pragma unroll
        for (int j = 0; j < 8; ++j) ss = fmaf(acc[j], acc[j], ss);
#pragma unroll
        for (int off = 1; off < 16; off <<= 1) ss += __shfl_xor(ss, off);
        float scale = rsqrtf(ss * (1.0f / 128.0f) + 1e-6f);
        const float* cb = cosk + ((size_t)b * NB + blkg) * 128 + cg * 8;
        const float* sb = sink + ((size_t)b * NB + blkg) * 128 + cg * 8;
        float part = 0.0f;
#pragma unroll
        for (int j = 0; j < 8; ++j) {
            float y  = acc[j] * scale * kn[j];
            float yp = __shfl_xor(y, 8);
            float rot = (cg < 8) ? -yp : yp;
            float z = fmaf(y, cb[j], rot * sb[j]);
            part = fmaf(z, qvr[j], part);
        }
#pragma unroll
        for (int off = 1; off < 16; off <<= 1) part += __shfl_xor(part, off);
        if (cg == 0)
            scores[((size_t)b * HKH + h) * NB + blkg] = part * 0.08838834764831845f;
    }
}

// ---------------- Kernel D: rank-by-counting top-k -> int32 mask ----------
__device__ inline bool read_mask(const void* amp, int mode, size_t idx) {
    if (mode == 1) return ((const int*)amp)[idx] != 0;
    if (mode == 2) return ((const unsigned int*)amp)[idx] != 0u;
    return ((const unsigned char*)amp)[idx] != 0;
}

__global__ __launch_bounds__(512) void topk_kernel(const float* __restrict__ scores,
                                                   const void* __restrict__ amraw,
                                                   const int* __restrict__ bbp,
                                                   int* __restrict__ out) {
    int b = blockIdx.x >> 3, h = blockIdx.x & 7;
    int t = threadIdx.x;
    __shared__ float sv[NB];
    __shared__ int mode_sh;

    if (t == 0) {
        // classify attention_mask dtype from raw bit patterns
        const unsigned int* w = (const unsigned int*)amraw;
        bool allint = true, allflt = true;
        for (int i = 0; i < 64; ++i) {
            unsigned int x = w[i];
            if (x != 0u && x != 1u) allint = false;
            if (x != 0u && x != 0x3f800000u) allflt = false;
        }
        mode_sh = allint ? 1 : (allflt ? 2 : 0);
    }
    __syncthreads();
    int mode = mode_sh;
    size_t rowoff = ((size_t)b * HKH + h) * NB;
    const float* src = scores + rowoff;
    for (int s = t; s < NB; s += 512)
        sv[s] = read_mask(amraw, mode, rowoff + s) ? src[s] : -1e20f;
    __syncthreads();

    int bb = bbp[0];
    if (bb > NB) bb = NB;
    if (bb < 1)  bb = 1;

    int e0 = t, e1 = t + 512;
    float v0 = sv[e0], v1 = sv[e1];
    int r0 = 0, r1 = 0;   // rank = #gt + #eq-at-lower-index
#pragma unroll 4
    for (int j4 = 0; j4 < 256; ++j4) {
        f4 w = *(const f4*)&sv[j4 * 4];
        int jb = j4 * 4;
        r0 += (w.x > v0) + (w.y > v0) + (w.z > v0) + (w.w > v0);
        r1 += (w.x > v1) + (w.y > v1) + (w.z > v1) + (w.w > v1);
        r0 += (w.x == v0 && jb + 0 < e0) + (w.y == v0 && jb + 1 < e0)
            + (w.z == v0 && jb + 2 < e0) + (w.w == v0 && jb + 3 < e0);
        r1 += (w.x == v1 && jb + 0 < e1) + (w.y == v1 && jb + 1 < e1)
            + (w.z == v1 && jb + 2 < e1) + (w.w == v1 && jb + 3 < e1);
    }
    int* dst = out + rowoff;
    bool am0 = read_mask(amraw, mode, rowoff + e0);
    bool am1 = read_mask(amraw, mode, rowoff + e1);
    dst[e0] = ((r0 < bb && am0)) ? 1 : 0;
    dst[e1] = ((r1 < bb && am1) || (e1 == NB - 1)) ? 1 : 0;
}

extern "C" void kernel_launch(void* const* d_in, const int* in_sizes, int n_in,
                              void* d_out, int out_size, void* d_ws, size_t ws_size,
                              hipStream_t stream) {
    (void)in_sizes; (void)n_in; (void)out_size; (void)ws_size;
    const float* k   = (const float*)d_in[0];
    const float* q   = (const float*)d_in[1];
    const float* Wq  = (const float*)d_in[2];
    const float* Wk  = (const float*)d_in[3];
    const float* qnw = (const float*)d_in[4];
    const float* knw = (const float*)d_in[5];
    const float* cq  = (const float*)d_in[6];
    const float* sq  = (const float*)d_in[7];
    const float* ck  = (const float*)d_in[8];
    const float* sk  = (const float*)d_in[9];
    const void*  am  = d_in[10];
    const int*   bb  = (const int*)d_in[11];
    int* out = (int*)d_out;

    float* qv     = (float*)d_ws;                 // 4*8*128 floats
    float* scores = qv + 4 * HKH * 128;           // 4*8*1024 floats

    qproj_kernel<<<32, 512, 0, stream>>>(q, Wq, qnw, cq, sq, qv);
    fused_kernel<<<1024, 256, 0, stream>>>(k, Wk, knw, ck, sk, qv, scores);
    topk_kernel<<<32, 512, 0, stream>>>(scores, am, bb, out);
}

// Round 7
// 258.051 us; speedup vs baseline: 1.2074x; 1.1070x over previous
//
#include <hip/hip_runtime.h>
#include <hip/hip_bf16.h>
#include <math.h>

#define NB   1024    // key blocks per batch
#define HKH  8       // Hk

typedef float f4 __attribute__((ext_vector_type(4)));

// ---------------- Kernel Q: query gate projection -----------------
// grid = B*HK = 32 blocks, 512 threads (4-way K split per output dim).
__global__ __launch_bounds__(512) void qproj_kernel(const float* __restrict__ q,
                                                    const float* __restrict__ Wq,
                                                    const float* __restrict__ qnw,
                                                    const float* __restrict__ cq,
                                                    const float* __restrict__ sq,
                                                    float* __restrict__ qv) {
    int b = blockIdx.x >> 3, h = blockIdx.x & 7;
    int t = threadIdx.x;
    int o = t & 127, seg = t >> 7;
    __shared__ float qs[512];
    __shared__ float part[4][128];
    __shared__ float red[2];
    __shared__ float ybuf[128];
    qs[t] = q[(size_t)b * 4096 + (size_t)h * 512 + t];
    __syncthreads();
    const float* wqp = Wq + (size_t)h * 512 * 128 + o;
    float acc = 0.0f;
    int g0 = seg * 128;
#pragma unroll 4
    for (int gi = g0; gi < g0 + 128; ++gi)
        acc = fmaf(qs[gi], wqp[(size_t)gi * 128], acc);
    part[seg][o] = acc;
    __syncthreads();
    if (t < 128) {
        float a = part[0][o] + part[1][o] + part[2][o] + part[3][o];
        ybuf[o] = a;
        float ss = a * a;
        for (int off = 32; off > 0; off >>= 1) ss += __shfl_xor(ss, off);
        if ((o & 63) == 0) red[o >> 6] = ss;
    }
    __syncthreads();
    if (t < 128) {
        float scale = rsqrtf((red[0] + red[1]) * (1.0f / 128.0f) + 1e-6f);
        float y  = ybuf[o] * scale * qnw[o];
        int op   = (o < 64) ? o + 64 : o - 64;
        float yp = ybuf[op] * scale * qnw[op];
        float rot = (o < 64) ? -yp : yp;
        qv[((size_t)b * HKH + h) * 128 + o] =
            fmaf(y, cq[b * 128 + o], rot * sq[b * 128 + o]);
    }
}

// ---------------- Fused kernel: contiguous pool + all-head GEMM -------------
// grid = B(4) * 256 tiles = 1024 wg (= exactly 4 wg/CU, one residency round),
// 256 threads. wg owns 4 consecutive key-blocks x ALL 8 heads.
// Phase 1: stream 1 MB fully contiguous (thread t = head t>>5, f4col t&31;
// 256 threads x 16B = one whole 4KB row per load step). Pool mean/max in regs.
// At[k][ (h^g(k))*4 + blk ] swizzled (g=(k>>3)&7): writes <=4-way, GEMM reads
// are same-address broadcasts within each 32-lane head group.
// Phase 2: per head M=4 x N=128, thread tile 4 rows x 4 cols: per k-step
// 1 LDS b128 broadcast + 1 coalesced global W b128 + 16 FMA (VALU-bound,
// W redundancy 1 -> 1 MB L2 per wg). Fused rmsnorm/rope/qdot epilogue.
__global__ __launch_bounds__(256) void fused_kernel(const float* __restrict__ kin,
                                                    const float* __restrict__ Wk,
                                                    const float* __restrict__ knw,
                                                    const float* __restrict__ cosk,
                                                    const float* __restrict__ sink,
                                                    const float* __restrict__ qv,
                                                    float* __restrict__ scores) {
    __shared__ float At[256][32];   // [k][(h^g(k))*4 + blk]
    int wg   = blockIdx.x;
    int tile = wg & 255;            // 4-block tile within batch
    int b    = wg >> 8;
    int t    = threadIdx.x;
    int h    = t >> 5;              // head (same in both phases)
    int c    = t & 31;              // f4-col within head (dims 4c..4c+3)

    // ---- Phase 1: pool 4 blocks, fully contiguous streaming ----
    {
        const float inv = 1.0f / 64.0f;
#pragma unroll
        for (int bi = 0; bi < 4; ++bi) {
            size_t row0 = (size_t)b * 65536 + (size_t)tile * 256 + (size_t)bi * 64;
            const f4* src = (const f4*)kin + row0 * 256 + t;
            f4 v = __builtin_nontemporal_load(src);
            f4 s = v, m = v;
#pragma unroll 8
            for (int r = 1; r < 64; ++r) {
                f4 u = __builtin_nontemporal_load(src + (size_t)r * 256);
                s += u;
                m.x = fmaxf(m.x, u.x); m.y = fmaxf(m.y, u.y);
                m.z = fmaxf(m.z, u.z); m.w = fmaxf(m.w, u.w);
            }
#pragma unroll
            for (int j = 0; j < 4; ++j) {
                int k0 = c * 4 + j;                 // mean dim
                int g  = (k0 >> 3) & 7;             // same for k0 and k0+128
                At[k0      ][((h ^ g) << 2) | bi] = s[j] * inv;
                At[k0 + 128][((h ^ g) << 2) | bi] = m[j];
            }
        }
    }
    __syncthreads();

    // ---- Phase 2: GEMM; head h: 4 rows (blocks) x cols 4c..4c+3, K=256 ----
    float acc[4][4];
#pragma unroll
    for (int i = 0; i < 4; ++i)
#pragma unroll
        for (int j = 0; j < 4; ++j) acc[i][j] = 0.0f;
    const float* wp = Wk + (size_t)h * 32768 + c * 4;
#pragma unroll 4
    for (int k = 0; k < 256; ++k) {
        int g = (k >> 3) & 7;
        f4 a = *(const f4*)&At[k][(h ^ g) << 2];    // broadcast within head
        f4 w = *(const f4*)(wp + (size_t)k * 128);  // coalesced 512B/head
#pragma unroll
        for (int i = 0; i < 4; ++i) {
            acc[i][0] = fmaf(a[i], w.x, acc[i][0]);
            acc[i][1] = fmaf(a[i], w.y, acc[i][1]);
            acc[i][2] = fmaf(a[i], w.z, acc[i][2]);
            acc[i][3] = fmaf(a[i], w.w, acc[i][3]);
        }
    }

    // ---- Epilogue: per-row rmsnorm + rope + dot(qv); 32-lane head group ----
    f4 kn  = *(const f4*)(knw + c * 4);
    f4 qvr = *(const f4*)(qv + ((size_t)b * HKH + h) * 128 + c * 4);
#pragma unroll
    for (int i = 0; i < 4; ++i) {
        int blkg = tile * 4 + i;
        float ss = 0.0f;
#pragma unroll
        for (int j = 0; j < 4; ++j) ss = fmaf(acc[i][j], acc[i][j], ss);
#pragma unroll
        for (int off = 1; off < 32; off <<= 1) ss += __shfl_xor(ss, off);
        float scale = rsqrtf(ss * (1.0f / 128.0f) + 1e-6f);
        f4 cb = *(const f4*)(cosk + ((size_t)b * NB + blkg) * 128 + c * 4);
        f4 sb = *(const f4*)(sink + ((size_t)b * NB + blkg) * 128 + c * 4);
        float part = 0.0f;
#pragma unroll
        for (int j = 0; j < 4; ++j) {
            float y  = acc[i][j] * scale * kn[j];
            float yp = __shfl_xor(y, 16);           // col partner o +/- 64
            float rot = (c < 16) ? -yp : yp;
            float z = fmaf(y, cb[j], rot * sb[j]);
            part = fmaf(z, qvr[j], part);
        }
#pragma unroll
        for (int off = 1; off < 32; off <<= 1) part += __shfl_xor(part, off);
        if (c == 0)
            scores[((size_t)b * HKH + h) * NB + blkg] = part * 0.08838834764831845f;
    }
}

// ---------------- Kernel D: rank-by-counting top-k -> int32 mask ----------
__device__ inline bool read_mask(const void* amp, int mode, size_t idx) {
    if (mode == 1) return ((const int*)amp)[idx] != 0;
    if (mode == 2) return ((const unsigned int*)amp)[idx] != 0u;
    return ((const unsigned char*)amp)[idx] != 0;
}

__global__ __launch_bounds__(512) void topk_kernel(const float* __restrict__ scores,
                                                   const void* __restrict__ amraw,
                                                   const int* __restrict__ bbp,
                                                   int* __restrict__ out) {
    int b = blockIdx.x >> 3, h = blockIdx.x & 7;
    int t = threadIdx.x;
    __shared__ float sv[NB];
    __shared__ int mode_sh;

    if (t == 0) {
        // classify attention_mask dtype from raw bit patterns
        const unsigned int* w = (const unsigned int*)amraw;
        bool allint = true, allflt = true;
        for (int i = 0; i < 64; ++i) {
            unsigned int x = w[i];
            if (x != 0u && x != 1u) allint = false;
            if (x != 0u && x != 0x3f800000u) allflt = false;
        }
        mode_sh = allint ? 1 : (allflt ? 2 : 0);
    }
    __syncthreads();
    int mode = mode_sh;
    size_t rowoff = ((size_t)b * HKH + h) * NB;
    const float* src = scores + rowoff;
    for (int s = t; s < NB; s += 512)
        sv[s] = read_mask(amraw, mode, rowoff + s) ? src[s] : -1e20f;
    __syncthreads();

    int bb = bbp[0];
    if (bb > NB) bb = NB;
    if (bb < 1)  bb = 1;

    int e0 = t, e1 = t + 512;
    float v0 = sv[e0], v1 = sv[e1];
    int r0 = 0, r1 = 0;   // rank = #gt + #eq-at-lower-index
#pragma unroll 4
    for (int j4 = 0; j4 < 256; ++j4) {
        f4 w = *(const f4*)&sv[j4 * 4];
        int jb = j4 * 4;
        r0 += (w.x > v0) + (w.y > v0) + (w.z > v0) + (w.w > v0);
        r1 += (w.x > v1) + (w.y > v1) + (w.z > v1) + (w.w > v1);
        r0 += (w.x == v0 && jb + 0 < e0) + (w.y == v0 && jb + 1 < e0)
            + (w.z == v0 && jb + 2 < e0) + (w.w == v0 && jb + 3 < e0);
        r1 += (w.x == v1 && jb + 0 < e1) + (w.y == v1 && jb + 1 < e1)
            + (w.z == v1 && jb + 2 < e1) + (w.w == v1 && jb + 3 < e1);
    }
    int* dst = out + rowoff;
    bool am0 = read_mask(amraw, mode, rowoff + e0);
    bool am1 = read_mask(amraw, mode, rowoff + e1);
    dst[e0] = ((r0 < bb && am0)) ? 1 : 0;
    dst[e1] = ((r1 < bb && am1) || (e1 == NB - 1)) ? 1 : 0;
}

extern "C" void kernel_launch(void* const* d_in, const int* in_sizes, int n_in,
                              void* d_out, int out_size, void* d_ws, size_t ws_size,
                              hipStream_t stream) {
    (void)in_sizes; (void)n_in; (void)out_size; (void)ws_size;
    const float* k   = (const float*)d_in[0];
    const float* q   = (const float*)d_in[1];
    const float* Wq  = (const float*)d_in[2];
    const float* Wk  = (const float*)d_in[3];
    const float* qnw = (const float*)d_in[4];
    const float* knw = (const float*)d_in[5];
    const float* cq  = (const float*)d_in[6];
    const float* sq  = (const float*)d_in[7];
    const float* ck  = (const float*)d_in[8];
    const float* sk  = (const float*)d_in[9];
    const void*  am  = d_in[10];
    const int*   bb  = (const int*)d_in[11];
    int* out = (int*)d_out;

    float* qv     = (float*)d_ws;                 // 4*8*128 floats
    float* scores = qv + 4 * HKH * 128;           // 4*8*1024 floats

    qproj_kernel<<<32, 512, 0, stream>>>(q, Wq, qnw, cq, sq, qv);
    fused_kernel<<<1024, 256, 0, stream>>>(k, Wk, knw, ck, sk, qv, scores);
    topk_kernel<<<32, 512, 0, stream>>>(scores, am, bb, out);
}